// Round 24
// baseline (403.802 us; speedup 1.0000x reference)
//
#include <hip/hip_runtime.h>

using bf16x8 = __attribute__((ext_vector_type(8))) short;
using f32x4  = __attribute__((ext_vector_type(4))) float;

#define DEV static __device__ __forceinline__

constexpr int SEQ    = 1040;
constexpr int MDIM   = 2048;
constexpr int NH     = 16;
constexpr int HD     = 128;
constexpr int NCACHE = 8320;
constexpr int LTOT   = NCACHE + SEQ;   // 9360
constexpr int NTILE  = 147;            // ceil(LTOT/64)
constexpr int KROWS  = NTILE * 64;     // 9408
constexpr int NQT2   = 9;              // ceil(SEQ/128)
constexpr int SPLITS = 6;              // 864 blocks; 25 tiles/block

DEV float b2f(unsigned short u) {
  union { unsigned int i; float f; } z; z.i = ((unsigned int)u) << 16; return z.f;
}
DEV unsigned short f2b(float f) {
  union { float f; unsigned int i; } z; z.f = f;
  return (unsigned short)((z.i + 0x7fffu + ((z.i >> 16) & 1u)) >> 16);
}
DEV unsigned int cvtpk(float lo, float hi) {
  unsigned int r;
  asm("v_cvt_pk_bf16_f32 %0, %1, %2" : "=v"(r) : "v"(lo), "v"(hi));
  return r;
}
union U4S8 { uint4 u; short s[8]; };

// ---------- convert x fp32 -> bf16 ----------
__global__ __launch_bounds__(256) void convx_k(
    const float* __restrict__ x, unsigned short* __restrict__ xb, int n8) {
  int i = blockIdx.x * 256 + threadIdx.x;
  if (i < n8) {
    const float* p = x + (size_t)i * 8;
    f32x4 a = *(const f32x4*)p, b = *(const f32x4*)(p + 4);
    uint4 u = make_uint4(cvtpk(a[0], a[1]), cvtpk(a[2], a[3]),
                         cvtpk(b[0], b[1]), cvtpk(b[2], b[3]));
    *(uint4*)(xb + (size_t)i * 8) = u;
  }
}

// ---------- K cache fp32 -> bf16 flat ----------
__global__ __launch_bounds__(256) void convk_k(
    const float* __restrict__ Kc, unsigned short* __restrict__ Kb, int n8) {
  int i = blockIdx.x * 256 + threadIdx.x;
  if (i < n8) {
    const float* p = Kc + (size_t)i * 8;
    f32x4 a = *(const f32x4*)p, b = *(const f32x4*)(p + 4);
    uint4 u = make_uint4(cvtpk(a[0], a[1]), cvtpk(a[2], a[3]),
                         cvtpk(b[0], b[1]), cvtpk(b[2], b[3]));
    *(uint4*)(Kb + (size_t)i * 8) = u;
  }
}

// ---------- V cache fp32 -> bf16 pre-transposed Vbt[tile][h][d][j] ----------
__global__ __launch_bounds__(256) void convvt_k(
    const float* __restrict__ Vc, unsigned short* __restrict__ Vbt) {
  __shared__ short T[64][136];
  const int tile = blockIdx.x, h = blockIdx.y;
  const int t = threadIdx.x;
  {
    int row = t >> 2, cq = t & 3;
    const float* p = Vc + (size_t)(tile * 64 + row) * MDIM + h * HD + cq * 32;
#pragma unroll
    for (int k = 0; k < 4; ++k) {
      f32x4 a = *(const f32x4*)(p + k * 8);
      f32x4 b = *(const f32x4*)(p + k * 8 + 4);
      *(uint4*)&T[row][cq * 32 + k * 8] =
          make_uint4(cvtpk(a[0], a[1]), cvtpk(a[2], a[3]), cvtpk(b[0], b[1]), cvtpk(b[2], b[3]));
    }
  }
  __syncthreads();
#pragma unroll
  for (int i = 0; i < 4; ++i) {
    int c = t + i * 256;
    int d = c >> 3, joct = c & 7;
    U4S8 u;
#pragma unroll
    for (int jj = 0; jj < 8; ++jj) u.s[jj] = T[joct * 8 + jj][d];
    *(uint4*)(Vbt + ((((size_t)tile * NH + h) * HD + d) * 64 + joct * 8)) = u.u;
  }
}

// ---------- convert+transpose W [k][n] fp32 -> Wt [n][k] bf16 (4 weights) ----------
__global__ __launch_bounds__(256) void convt_k(
    const float* __restrict__ W0, const float* __restrict__ W1,
    const float* __restrict__ W2, const float* __restrict__ W3,
    unsigned short* __restrict__ T0, unsigned short* __restrict__ T1,
    unsigned short* __restrict__ T2, unsigned short* __restrict__ T3) {
  __shared__ short T[64][72];
  const int zz = blockIdx.z;
  const float* W = (zz == 0) ? W0 : (zz == 1) ? W1 : (zz == 2) ? W2 : W3;
  unsigned short* O = (zz == 0) ? T0 : (zz == 1) ? T1 : (zz == 2) ? T2 : T3;
  const int r0 = blockIdx.y * 64, c0 = blockIdx.x * 64;
  const int t = threadIdx.x;
  {
    int row = t >> 2, cq = t & 3;
    const float* p = W + (size_t)(r0 + row) * MDIM + c0 + cq * 16;
    f32x4 a = *(const f32x4*)(p);
    f32x4 b = *(const f32x4*)(p + 4);
    f32x4 c = *(const f32x4*)(p + 8);
    f32x4 d = *(const f32x4*)(p + 12);
    *(uint4*)&T[row][cq * 16] =
        make_uint4(cvtpk(a[0], a[1]), cvtpk(a[2], a[3]), cvtpk(b[0], b[1]), cvtpk(b[2], b[3]));
    *(uint4*)&T[row][cq * 16 + 8] =
        make_uint4(cvtpk(c[0], c[1]), cvtpk(c[2], c[3]), cvtpk(d[0], d[1]), cvtpk(d[2], d[3]));
  }
  __syncthreads();
  {
    int c = t >> 2, kq = t & 3;
    U4S8 v0, v1;
#pragma unroll
    for (int i = 0; i < 8; ++i) v0.s[i] = T[kq * 16 + i][c];
#pragma unroll
    for (int i = 0; i < 8; ++i) v1.s[i] = T[kq * 16 + 8 + i][c];
    unsigned short* op = O + (size_t)(c0 + c) * MDIM + r0 + kq * 16;
    *(uint4*)(op) = v0.u;
    *(uint4*)(op + 8) = v1.u;
  }
}

// ---------- fused QKV GEMM (r22, passing) ----------
__global__ __launch_bounds__(256) void gemm_qkv_k(
    const unsigned short* __restrict__ xb,
    const unsigned short* __restrict__ Wtq, const unsigned short* __restrict__ Wtk,
    const unsigned short* __restrict__ Wtv,
    const float* __restrict__ bq, const float* __restrict__ bk, const float* __restrict__ bv,
    unsigned short* __restrict__ Qb, unsigned short* __restrict__ Kb, unsigned short* __restrict__ Vbt) {
  __shared__ short As[64][72];
  __shared__ short Bs[128][72];
  const int tid = threadIdx.x;
  const int l = tid & 63, wv = tid >> 6;
  const int l16 = l & 15, kl = l >> 4;
  const int m0 = blockIdx.y * 64;
  const int n0g = blockIdx.x * 128;
  const int which = n0g >> 11;
  const int n0 = n0g & 2047;
  const unsigned short* Wt = (which == 0) ? Wtq : (which == 1) ? Wtk : Wtv;
  const float* bias = (which == 0) ? bq : (which == 1) ? bk : bv;
  const int wm = (wv >> 1) * 32, wn = (wv & 1) * 64;
  f32x4 acc[2][4] = {};
  for (int k0 = 0; k0 < MDIM; k0 += 64) {
    {
      int m = tid >> 2, kq = tid & 3;
      int row = m0 + m;
      uint4 v0 = make_uint4(0, 0, 0, 0), v1 = make_uint4(0, 0, 0, 0);
      if (row < SEQ) {
        const unsigned short* p = xb + (size_t)row * MDIM + k0 + kq * 16;
        v0 = *(const uint4*)p;
        v1 = *(const uint4*)(p + 8);
      }
      *(uint4*)&As[m][kq * 16] = v0;
      *(uint4*)&As[m][kq * 16 + 8] = v1;
    }
    {
      int n = tid >> 1, kq = tid & 1;
      const unsigned short* p = Wt + (size_t)(n0 + n) * MDIM + k0 + kq * 32;
      uint4 v0 = *(const uint4*)p, v1 = *(const uint4*)(p + 8);
      uint4 v2 = *(const uint4*)(p + 16), v3 = *(const uint4*)(p + 24);
      *(uint4*)&Bs[n][kq * 32] = v0;
      *(uint4*)&Bs[n][kq * 32 + 8] = v1;
      *(uint4*)&Bs[n][kq * 32 + 16] = v2;
      *(uint4*)&Bs[n][kq * 32 + 24] = v3;
    }
    __syncthreads();
#pragma unroll
    for (int kk = 0; kk < 2; ++kk) {
      bf16x8 aF[2], bF[4];
#pragma unroll
      for (int mi = 0; mi < 2; ++mi)
        aF[mi] = *(const bf16x8*)&As[wm + mi * 16 + l16][kk * 32 + kl * 8];
#pragma unroll
      for (int ni = 0; ni < 4; ++ni)
        bF[ni] = *(const bf16x8*)&Bs[wn + ni * 16 + l16][kk * 32 + kl * 8];
#pragma unroll
      for (int mi = 0; mi < 2; ++mi)
#pragma unroll
        for (int ni = 0; ni < 4; ++ni)
          acc[mi][ni] = __builtin_amdgcn_mfma_f32_16x16x32_bf16(
              aF[mi], bF[ni], acc[mi][ni], 0, 0, 0);
    }
    __syncthreads();
  }
#pragma unroll
  for (int ni = 0; ni < 4; ++ni) {
    const int col = n0 + wn + ni * 16 + l16;
    const float bb = bias[col];
    const int hh = col >> 7, dd = col & 127;
#pragma unroll
    for (int mi = 0; mi < 2; ++mi) {
      const int rowb = m0 + wm + mi * 16 + kl * 4;
#pragma unroll
      for (int r = 0; r < 4; ++r) {
        const int row = rowb + r;
        if (row >= SEQ) continue;
        const unsigned short val = f2b(acc[mi][ni][r] + bb);
        if (which == 0) {
          Qb[((size_t)hh * SEQ + row) * HD + dd] = val;
        } else if (which == 1) {
          Kb[(size_t)(NCACHE + row) * MDIM + col] = val;
        } else {
          const int g = NCACHE + row;
          Vbt[(((size_t)(g >> 6) * NH + hh) * HD + dd) * 64 + (g & 63)] = val;
        }
      }
    }
  }
}

// ---------- Wo GEMM (r20, passing) ----------
__global__ __launch_bounds__(256) void gemm_o_k(
    const unsigned short* __restrict__ Ab, const unsigned short* __restrict__ Wt,
    const float* __restrict__ bias, float* __restrict__ outp) {
  __shared__ short As[64][72];
  __shared__ short Bs[128][72];
  const int tid = threadIdx.x;
  const int l = tid & 63, wv = tid >> 6;
  const int l16 = l & 15, kl = l >> 4;
  const int m0 = blockIdx.y * 64, n0 = blockIdx.x * 128;
  const int wm = (wv >> 1) * 32, wn = (wv & 1) * 64;
  f32x4 acc[2][4] = {};
  for (int k0 = 0; k0 < MDIM; k0 += 64) {
    {
      int m = tid >> 2, kq = tid & 3;
      int row = m0 + m, k = k0 + kq * 16;
      uint4 v0 = make_uint4(0, 0, 0, 0), v1 = make_uint4(0, 0, 0, 0);
      if (row < SEQ) {
        const unsigned short* p = Ab + ((size_t)(k >> 7) * SEQ + row) * HD + (k & 127);
        v0 = *(const uint4*)p;
        v1 = *(const uint4*)(p + 8);
      }
      *(uint4*)&As[m][kq * 16] = v0;
      *(uint4*)&As[m][kq * 16 + 8] = v1;
    }
    {
      int n = tid >> 1, kq = tid & 1;
      const unsigned short* p = Wt + (size_t)(n0 + n) * MDIM + k0 + kq * 32;
      uint4 v0 = *(const uint4*)p, v1 = *(const uint4*)(p + 8);
      uint4 v2 = *(const uint4*)(p + 16), v3 = *(const uint4*)(p + 24);
      *(uint4*)&Bs[n][kq * 32] = v0;
      *(uint4*)&Bs[n][kq * 32 + 8] = v1;
      *(uint4*)&Bs[n][kq * 32 + 16] = v2;
      *(uint4*)&Bs[n][kq * 32 + 24] = v3;
    }
    __syncthreads();
#pragma unroll
    for (int kk = 0; kk < 2; ++kk) {
      bf16x8 aF[2], bF[4];
#pragma unroll
      for (int mi = 0; mi < 2; ++mi)
        aF[mi] = *(const bf16x8*)&As[wm + mi * 16 + l16][kk * 32 + kl * 8];
#pragma unroll
      for (int ni = 0; ni < 4; ++ni)
        bF[ni] = *(const bf16x8*)&Bs[wn + ni * 16 + l16][kk * 32 + kl * 8];
#pragma unroll
      for (int mi = 0; mi < 2; ++mi)
#pragma unroll
        for (int ni = 0; ni < 4; ++ni)
          acc[mi][ni] = __builtin_amdgcn_mfma_f32_16x16x32_bf16(
              aF[mi], bF[ni], acc[mi][ni], 0, 0, 0);
    }
    __syncthreads();
  }
#pragma unroll
  for (int ni = 0; ni < 4; ++ni) {
    const int col = n0 + wn + ni * 16 + l16;
    const float bb = bias[col];
#pragma unroll
    for (int mi = 0; mi < 2; ++mi) {
      const int rowb = m0 + wm + mi * 16 + kl * 4;
#pragma unroll
      for (int r = 0; r < 4; ++r) {
        const int row = rowb + r;
        if (row >= SEQ) continue;
        outp[(size_t)row * MDIM + col] = acc[mi][ni][r] + bb;
      }
    }
  }
}

// ---------- RMSNorm + RoPE (r22, passing) ----------
__global__ __launch_bounds__(256) void rmsrope_k(
    unsigned short* __restrict__ Qb, unsigned short* __restrict__ Kb,
    const float* __restrict__ gq, const float* __restrict__ gk,
    const float* __restrict__ fr) {
  const int s = blockIdx.x, which = blockIdx.y;
  const float* g = which ? gk : gq;
  __shared__ float cs[64], sn[64], red[4];
  const int t = threadIdx.x;
  if (t < 64) {
    float a = fr[s * 64 + t];
    cs[t] = cosf(a);
    sn[t] = sinf(a);
  }
  const int c0 = t * 8;
  const int hh = c0 >> 7, dd = c0 & 127, p0 = dd >> 1;
  unsigned short* ptr = which
      ? Kb + (size_t)(NCACHE + s) * MDIM + c0
      : Qb + ((size_t)hh * SEQ + s) * HD + dd;
  bf16x8 v = *(const bf16x8*)ptr;
  float y[8];
#pragma unroll
  for (int i = 0; i < 8; ++i) y[i] = b2f((unsigned short)v[i]);
  float ssq = 0.f;
#pragma unroll
  for (int i = 0; i < 8; ++i) ssq += y[i] * y[i];
#pragma unroll
  for (int off = 32; off; off >>= 1) ssq += __shfl_xor(ssq, off);
  if ((t & 63) == 0) red[t >> 6] = ssq;
  __syncthreads();
  const float var = (red[0] + red[1] + red[2] + red[3]) * (1.0f / MDIM);
  const float rs = rsqrtf(var + 1e-6f);
  bf16x8 ov;
#pragma unroll
  for (int i = 0; i < 4; ++i) {
    float e = b2f(f2b(y[2 * i] * rs)) * g[c0 + 2 * i];
    float o = b2f(f2b(y[2 * i + 1] * rs)) * g[c0 + 2 * i + 1];
    float C = cs[p0 + i], S = sn[p0 + i];
    ov[2 * i]     = (short)f2b(e * C - o * S);
    ov[2 * i + 1] = (short)f2b(e * S + o * C);
  }
  *(bf16x8*)ptr = ov;
}

// ---------- flash attention v9: log2-domain softmax, cvtpk P-write,
//            3 barriers, setprio, defer-max (8 in log2 units) ----------
__global__ __launch_bounds__(512) void attn_part9_k(
    const unsigned short* __restrict__ Qb, const unsigned short* __restrict__ Kb,
    const unsigned short* __restrict__ Vbt, unsigned short* __restrict__ Opart,
    float* __restrict__ ml, int chunk, int S) {
  __shared__ short UN[9216];        // Kl: UN[j*136+d]; Pl: UN[(w*16+r)*72+c]
  __shared__ short Vt[128][72];
  const int b = blockIdx.x;
  const int xcd = b & 7;
  const int r_ = b >> 3;
  const int qt = r_ % NQT2;
  const int g = (r_ / NQT2) * 8 + xcd;
  const int h = g & (NH - 1);
  const int z = g >> 4;
  const int tid = threadIdx.x, wv = tid >> 6, l = tid & 63;
  const int l16 = l & 15, kl = l >> 4;
  // log2-domain scale: (1/sqrt(128)) * log2(e)
  const float SCALE2 = 0.12751551815656266f;

  const int c0 = z * chunk;
  const int cend = min(c0 + chunk, LTOT);

  int qrow = qt * 128 + wv * 16 + l16;
  if (qrow > SEQ - 1) qrow = SEQ - 1;
  bf16x8 qf[4];
#pragma unroll
  for (int kk = 0; kk < 4; ++kk)
    qf[kk] = *(const bf16x8*)(Qb + ((size_t)h * SEQ + qrow) * HD + kk * 32 + kl * 8);

  f32x4 oacc[8] = {};
  float mrow[4] = {-1e30f, -1e30f, -1e30f, -1e30f};
  float lrow[4] = {0.f, 0.f, 0.f, 0.f};

  const int j0 = tid & 63, dq0 = tid >> 6, dq1 = (tid + 512) >> 6;
  const int dV0 = tid >> 3, dV1 = (tid + 512) >> 3, jo = tid & 7;
  const int hofs = h * HD;

  for (int kv0 = c0; kv0 < cend; kv0 += 64) {
    {
      const size_t krow = (size_t)(kv0 + j0) * MDIM + hofs;
      uint4 k0v = *(const uint4*)(Kb + krow + dq0 * 8);
      uint4 k1v = *(const uint4*)(Kb + krow + dq1 * 8);
      const size_t vbase = (((size_t)(kv0 >> 6) * NH + h) * HD) * 64;
      uint4 v0v = *(const uint4*)(Vbt + vbase + (size_t)dV0 * 64 + jo * 8);
      uint4 v1v = *(const uint4*)(Vbt + vbase + (size_t)dV1 * 64 + jo * 8);
      *(uint4*)&UN[j0 * 136 + dq0 * 8] = k0v;
      *(uint4*)&UN[j0 * 136 + dq1 * 8] = k1v;
      *(uint4*)&Vt[dV0][jo * 8] = v0v;
      *(uint4*)&Vt[dV1][jo * 8] = v1v;
    }
    __syncthreads();                                   // bar1: K/V staged

    f32x4 sa[4] = {};
    __builtin_amdgcn_s_setprio(1);
#pragma unroll
    for (int ni = 0; ni < 4; ++ni)
#pragma unroll
      for (int kk = 0; kk < 4; ++kk) {
        bf16x8 bK = *(const bf16x8*)&UN[(ni * 16 + l16) * 136 + kk * 32 + kl * 8];
        sa[ni] = __builtin_amdgcn_mfma_f32_16x16x32_bf16(qf[kk], bK, sa[ni], 0, 0, 0);
      }
    __builtin_amdgcn_s_setprio(0);
    __syncthreads();                                   // bar2: QK reads done (P aliases Kl)

    float sv[4][4];
    float pm[4] = {-1e30f, -1e30f, -1e30f, -1e30f};
#pragma unroll
    for (int ni = 0; ni < 4; ++ni) {
      int jg = kv0 + ni * 16 + l16;
      bool valid = jg < LTOT;
#pragma unroll
      for (int r = 0; r < 4; ++r) {
        float xs = valid ? sa[ni][r] * SCALE2 : -1e30f;   // log2 units
        sv[ni][r] = xs;
        pm[r] = fmaxf(pm[r], xs);
      }
    }
#pragma unroll
    for (int off = 1; off < 16; off <<= 1)
#pragma unroll
      for (int r = 0; r < 4; ++r) pm[r] = fmaxf(pm[r], __shfl_xor(pm[r], off));

    // defer-max: rescale only when a row max grew by > 8 (log2) => P <= 2^8
    bool grow = (pm[0] > mrow[0] + 8.f) || (pm[1] > mrow[1] + 8.f) ||
                (pm[2] > mrow[2] + 8.f) || (pm[3] > mrow[3] + 8.f);
    if (__any(grow)) {
#pragma unroll
      for (int r = 0; r < 4; ++r) {
        float mn = fmaxf(mrow[r], pm[r]);
        float sc = exp2f(mrow[r] - mn);
        mrow[r] = mn;
        lrow[r] *= sc;
#pragma unroll
        for (int di = 0; di < 8; ++di) oacc[di][r] *= sc;
      }
    }

    float ps[4] = {0.f, 0.f, 0.f, 0.f};
#pragma unroll
    for (int ni = 0; ni < 4; ++ni)
#pragma unroll
      for (int r = 0; r < 4; ++r) {
        float p = exp2f(sv[ni][r] - mrow[r]);   // single v_exp_f32
        sv[ni][r] = p;
        ps[r] += p;
      }
#pragma unroll
    for (int off = 1; off < 16; off <<= 1)
#pragma unroll
      for (int r = 0; r < 4; ++r) ps[r] += __shfl_xor(ps[r], off);
#pragma unroll
    for (int r = 0; r < 4; ++r) lrow[r] += ps[r];

    // P write via packed cvt: rows kl*4 + {0,1,2,3}, col ni*16+l16 (wave-private slab)
#pragma unroll
    for (int ni = 0; ni < 4; ++ni) {
      unsigned int u01 = cvtpk(sv[ni][0], sv[ni][1]);
      unsigned int u23 = cvtpk(sv[ni][2], sv[ni][3]);
      const int colb = ni * 16 + l16;
      const int rowb = wv * 16 + kl * 4;
      UN[(rowb + 0) * 72 + colb] = (short)(u01 & 0xffffu);
      UN[(rowb + 1) * 72 + colb] = (short)(u01 >> 16);
      UN[(rowb + 2) * 72 + colb] = (short)(u23 & 0xffffu);
      UN[(rowb + 3) * 72 + colb] = (short)(u23 >> 16);
    }

    __builtin_amdgcn_s_setprio(1);
#pragma unroll
    for (int di = 0; di < 8; ++di)
#pragma unroll
      for (int k2 = 0; k2 < 2; ++k2) {
        bf16x8 aP = *(const bf16x8*)&UN[(wv * 16 + l16) * 72 + k2 * 32 + kl * 8];
        bf16x8 bV = *(const bf16x8*)&Vt[di * 16 + l16][k2 * 32 + kl * 8];
        oacc[di] = __builtin_amdgcn_mfma_f32_16x16x32_bf16(aP, bV, oacc[di], 0, 0, 0);
      }
    __builtin_amdgcn_s_setprio(0);
    __syncthreads();                                   // bar3: all reads done; UN/Vt free
  }

  const size_t pbase = (((size_t)z * NH + h) * NQT2 + qt);
  const int row = wv * 16 + kl * 4;
#pragma unroll
  for (int r = 0; r < 4; ++r) {
    unsigned short* Op = Opart + (pbase * 128 + row + r) * HD;
#pragma unroll
    for (int di = 0; di < 8; ++di) Op[di * 16 + l16] = f2b(oacc[di][r]);
    ml[(pbase * 2 + 0) * 128 + row + r] = mrow[r];     // log2-domain m
    ml[(pbase * 2 + 1) * 128 + row + r] = lrow[r];
  }
}

// ---------- merge bf16 partials (log2-domain m) -> bf16 O in Qb ----------
__global__ __launch_bounds__(512) void attn_merge4_k(
    const unsigned short* __restrict__ Opart, const float* __restrict__ ml,
    unsigned short* __restrict__ Qb, int S) {
  const int qt = blockIdx.x, h = blockIdx.y;
  const int t = threadIdx.x;
  const int row = t >> 2, d0 = (t & 3) * 32;
  const int q = qt * 128 + row;

  float M = -1e30f;
  for (int s = 0; s < S; ++s) {
    const size_t pbase = (((size_t)s * NH + h) * NQT2 + qt);
    M = fmaxf(M, ml[(pbase * 2 + 0) * 128 + row]);
  }
  float L = 0.f;
  float o[32];
#pragma unroll
  for (int i = 0; i < 32; ++i) o[i] = 0.f;
  for (int s = 0; s < S; ++s) {
    const size_t pbase = (((size_t)s * NH + h) * NQT2 + qt);
    const float ms = ml[(pbase * 2 + 0) * 128 + row];
    const float ls = ml[(pbase * 2 + 1) * 128 + row];
    const float w = exp2f(ms - M);                    // log2-domain merge
    L += w * ls;
    const unsigned short* Op = Opart + (pbase * 128 + row) * HD + d0;
#pragma unroll
    for (int c = 0; c < 4; ++c) {
      bf16x8 v = *(const bf16x8*)(Op + c * 8);
#pragma unroll
      for (int i = 0; i < 8; ++i) o[c * 8 + i] += w * b2f((unsigned short)v[i]);
    }
  }
  if (q < SEQ) {
    const float inv = 1.f / L;
    unsigned short* op = Qb + ((size_t)h * SEQ + q) * HD + d0;
#pragma unroll
    for (int i = 0; i < 32; ++i) op[i] = f2b(o[i] * inv);
  }
}

extern "C" void kernel_launch(void* const* d_in, const int* in_sizes, int n_in,
                              void* d_out, int out_size, void* d_ws, size_t ws_size,
                              hipStream_t stream) {
  const float* x  = (const float*)d_in[0];
  const float* fr = (const float*)d_in[2];
  const float* Kc = (const float*)d_in[3];
  const float* Vc = (const float*)d_in[4];
  const float* Wq = (const float*)d_in[5];
  const float* bq = (const float*)d_in[6];
  const float* Wk = (const float*)d_in[7];
  const float* bk = (const float*)d_in[8];
  const float* Wv = (const float*)d_in[9];
  const float* bv = (const float*)d_in[10];
  const float* Wo = (const float*)d_in[11];
  const float* bo = (const float*)d_in[12];
  const float* gq = (const float*)d_in[13];
  const float* gk = (const float*)d_in[14];

  unsigned short* xb  = (unsigned short*)d_ws;
  unsigned short* Wto = xb + (size_t)SEQ * MDIM;
  unsigned short* Qb  = Wto + (size_t)MDIM * MDIM;
  unsigned short* Kb  = Qb + (size_t)NH * SEQ * HD;
  unsigned short* Vbt = Kb + (size_t)KROWS * MDIM;
  unsigned short* Wtq = Vbt + (size_t)NTILE * NH * HD * 64;
  unsigned short* Wtk = Wtq + (size_t)MDIM * MDIM;
  unsigned short* Wtv = Wtk + (size_t)MDIM * MDIM;

  const int S = SPLITS;
  unsigned short* Opart = Wtq;   // aliases Wt zone (dead after gemm_qkv)
  float* ml = (float*)(Opart + (size_t)S * NH * NQT2 * 128 * HD);

  hipMemsetAsync(Vbt + (size_t)(NTILE - 1) * NH * HD * 64, 0,
                 (size_t)NH * HD * 64 * 2, stream);

  const int n8x = SEQ * MDIM / 8;
  const int n8k = NCACHE * MDIM / 8;
  convx_k<<<dim3((n8x + 255) / 256), 256, 0, stream>>>(x, xb, n8x);
  convk_k<<<dim3((n8k + 255) / 256), 256, 0, stream>>>(Kc, Kb, n8k);
  convvt_k<<<dim3(NCACHE / 64, NH), 256, 0, stream>>>(Vc, Vbt);
  convt_k<<<dim3(32, 32, 4), 256, 0, stream>>>(Wq, Wk, Wv, Wo, Wtq, Wtk, Wtv, Wto);

  gemm_qkv_k<<<dim3(48, 17), 256, 0, stream>>>(xb, Wtq, Wtk, Wtv, bq, bk, bv, Qb, Kb, Vbt);
  rmsrope_k<<<dim3(SEQ, 2), 256, 0, stream>>>(Qb, Kb, gq, gk, fr);

  const int chunk = ((NTILE + S - 1) / S) * 64;    // 25 tiles
  attn_part9_k<<<dim3(NQT2 * NH * S), 512, 0, stream>>>(Qb, Kb, Vbt, Opart, ml, chunk, S);
  attn_merge4_k<<<dim3(NQT2, NH), 512, 0, stream>>>(Opart, ml, Qb, S);

  gemm_o_k<<<dim3(16, 17), 256, 0, stream>>>(Qb, Wto, bo, (float*)d_out);
}

// Round 25
// 394.262 us; speedup vs baseline: 1.0242x; 1.0242x over previous
//
#include <hip/hip_runtime.h>

using bf16x8 = __attribute__((ext_vector_type(8))) short;
using f32x4  = __attribute__((ext_vector_type(4))) float;

#define DEV static __device__ __forceinline__

constexpr int SEQ    = 1040;
constexpr int MDIM   = 2048;
constexpr int NH     = 16;
constexpr int HD     = 128;
constexpr int NCACHE = 8320;
constexpr int LTOT   = NCACHE + SEQ;   // 9360
constexpr int NTILE  = 147;            // ceil(LTOT/64)
constexpr int KROWS  = NTILE * 64;     // 9408
constexpr int NQT2   = 9;              // ceil(SEQ/128)
constexpr int SPLITS = 6;              // 864 blocks; 25 tiles/block

DEV float b2f(unsigned short u) {
  union { unsigned int i; float f; } z; z.i = ((unsigned int)u) << 16; return z.f;
}
DEV unsigned short f2b(float f) {
  union { float f; unsigned int i; } z; z.f = f;
  return (unsigned short)((z.i + 0x7fffu + ((z.i >> 16) & 1u)) >> 16);
}
DEV unsigned int cvtpk(float lo, float hi) {
  unsigned int r;
  asm("v_cvt_pk_bf16_f32 %0, %1, %2" : "=v"(r) : "v"(lo), "v"(hi));
  return r;
}
union U4S8 { uint4 u; short s[8]; };

// ---------- fused flat convert: x (n8x) then K cache (n8k), fp32 -> bf16 ----------
__global__ __launch_bounds__(256) void convflat_k(
    const float* __restrict__ x, unsigned short* __restrict__ xb, int n8x,
    const float* __restrict__ Kc, unsigned short* __restrict__ Kb, int n8k) {
  int i = blockIdx.x * 256 + threadIdx.x;
  const float* src;
  unsigned short* dst;
  int idx;
  if (i < n8x) { src = x; dst = xb; idx = i; }
  else if (i < n8x + n8k) { src = Kc; dst = Kb; idx = i - n8x; }
  else return;
  const float* p = src + (size_t)idx * 8;
  f32x4 a = *(const f32x4*)p, b = *(const f32x4*)(p + 4);
  uint4 u = make_uint4(cvtpk(a[0], a[1]), cvtpk(a[2], a[3]),
                       cvtpk(b[0], b[1]), cvtpk(b[2], b[3]));
  *(uint4*)(dst + (size_t)idx * 8) = u;
}

// ---------- V cache fp32 -> bf16 pre-transposed Vbt[tile][h][d][j] ----------
__global__ __launch_bounds__(256) void convvt_k(
    const float* __restrict__ Vc, unsigned short* __restrict__ Vbt) {
  __shared__ short T[64][136];
  const int tile = blockIdx.x, h = blockIdx.y;
  const int t = threadIdx.x;
  {
    int row = t >> 2, cq = t & 3;
    const float* p = Vc + (size_t)(tile * 64 + row) * MDIM + h * HD + cq * 32;
#pragma unroll
    for (int k = 0; k < 4; ++k) {
      f32x4 a = *(const f32x4*)(p + k * 8);
      f32x4 b = *(const f32x4*)(p + k * 8 + 4);
      *(uint4*)&T[row][cq * 32 + k * 8] =
          make_uint4(cvtpk(a[0], a[1]), cvtpk(a[2], a[3]), cvtpk(b[0], b[1]), cvtpk(b[2], b[3]));
    }
  }
  __syncthreads();
#pragma unroll
  for (int i = 0; i < 4; ++i) {
    int c = t + i * 256;
    int d = c >> 3, joct = c & 7;
    U4S8 u;
#pragma unroll
    for (int jj = 0; jj < 8; ++jj) u.s[jj] = T[joct * 8 + jj][d];
    *(uint4*)(Vbt + ((((size_t)tile * NH + h) * HD + d) * 64 + joct * 8)) = u.u;
  }
}

// ---------- convert+transpose W [k][n] fp32 -> Wt [n][k] bf16 (4 weights) ----------
__global__ __launch_bounds__(256) void convt_k(
    const float* __restrict__ W0, const float* __restrict__ W1,
    const float* __restrict__ W2, const float* __restrict__ W3,
    unsigned short* __restrict__ T0, unsigned short* __restrict__ T1,
    unsigned short* __restrict__ T2, unsigned short* __restrict__ T3) {
  __shared__ short T[64][72];
  const int zz = blockIdx.z;
  const float* W = (zz == 0) ? W0 : (zz == 1) ? W1 : (zz == 2) ? W2 : W3;
  unsigned short* O = (zz == 0) ? T0 : (zz == 1) ? T1 : (zz == 2) ? T2 : T3;
  const int r0 = blockIdx.y * 64, c0 = blockIdx.x * 64;
  const int t = threadIdx.x;
  {
    int row = t >> 2, cq = t & 3;
    const float* p = W + (size_t)(r0 + row) * MDIM + c0 + cq * 16;
    f32x4 a = *(const f32x4*)(p);
    f32x4 b = *(const f32x4*)(p + 4);
    f32x4 c = *(const f32x4*)(p + 8);
    f32x4 d = *(const f32x4*)(p + 12);
    *(uint4*)&T[row][cq * 16] =
        make_uint4(cvtpk(a[0], a[1]), cvtpk(a[2], a[3]), cvtpk(b[0], b[1]), cvtpk(b[2], b[3]));
    *(uint4*)&T[row][cq * 16 + 8] =
        make_uint4(cvtpk(c[0], c[1]), cvtpk(c[2], c[3]), cvtpk(d[0], d[1]), cvtpk(d[2], d[3]));
  }
  __syncthreads();
  {
    int c = t >> 2, kq = t & 3;
    U4S8 v0, v1;
#pragma unroll
    for (int i = 0; i < 8; ++i) v0.s[i] = T[kq * 16 + i][c];
#pragma unroll
    for (int i = 0; i < 8; ++i) v1.s[i] = T[kq * 16 + 8 + i][c];
    unsigned short* op = O + (size_t)(c0 + c) * MDIM + r0 + kq * 16;
    *(uint4*)(op) = v0.u;
    *(uint4*)(op + 8) = v1.u;
  }
}

// ---------- fused QKV GEMM (r22, passing) ----------
__global__ __launch_bounds__(256) void gemm_qkv_k(
    const unsigned short* __restrict__ xb,
    const unsigned short* __restrict__ Wtq, const unsigned short* __restrict__ Wtk,
    const unsigned short* __restrict__ Wtv,
    const float* __restrict__ bq, const float* __restrict__ bk, const float* __restrict__ bv,
    unsigned short* __restrict__ Qb, unsigned short* __restrict__ Kb, unsigned short* __restrict__ Vbt) {
  __shared__ short As[64][72];
  __shared__ short Bs[128][72];
  const int tid = threadIdx.x;
  const int l = tid & 63, wv = tid >> 6;
  const int l16 = l & 15, kl = l >> 4;
  const int m0 = blockIdx.y * 64;
  const int n0g = blockIdx.x * 128;
  const int which = n0g >> 11;
  const int n0 = n0g & 2047;
  const unsigned short* Wt = (which == 0) ? Wtq : (which == 1) ? Wtk : Wtv;
  const float* bias = (which == 0) ? bq : (which == 1) ? bk : bv;
  const int wm = (wv >> 1) * 32, wn = (wv & 1) * 64;
  f32x4 acc[2][4] = {};
  for (int k0 = 0; k0 < MDIM; k0 += 64) {
    {
      int m = tid >> 2, kq = tid & 3;
      int row = m0 + m;
      uint4 v0 = make_uint4(0, 0, 0, 0), v1 = make_uint4(0, 0, 0, 0);
      if (row < SEQ) {
        const unsigned short* p = xb + (size_t)row * MDIM + k0 + kq * 16;
        v0 = *(const uint4*)p;
        v1 = *(const uint4*)(p + 8);
      }
      *(uint4*)&As[m][kq * 16] = v0;
      *(uint4*)&As[m][kq * 16 + 8] = v1;
    }
    {
      int n = tid >> 1, kq = tid & 1;
      const unsigned short* p = Wt + (size_t)(n0 + n) * MDIM + k0 + kq * 32;
      uint4 v0 = *(const uint4*)p, v1 = *(const uint4*)(p + 8);
      uint4 v2 = *(const uint4*)(p + 16), v3 = *(const uint4*)(p + 24);
      *(uint4*)&Bs[n][kq * 32] = v0;
      *(uint4*)&Bs[n][kq * 32 + 8] = v1;
      *(uint4*)&Bs[n][kq * 32 + 16] = v2;
      *(uint4*)&Bs[n][kq * 32 + 24] = v3;
    }
    __syncthreads();
#pragma unroll
    for (int kk = 0; kk < 2; ++kk) {
      bf16x8 aF[2], bF[4];
#pragma unroll
      for (int mi = 0; mi < 2; ++mi)
        aF[mi] = *(const bf16x8*)&As[wm + mi * 16 + l16][kk * 32 + kl * 8];
#pragma unroll
      for (int ni = 0; ni < 4; ++ni)
        bF[ni] = *(const bf16x8*)&Bs[wn + ni * 16 + l16][kk * 32 + kl * 8];
#pragma unroll
      for (int mi = 0; mi < 2; ++mi)
#pragma unroll
        for (int ni = 0; ni < 4; ++ni)
          acc[mi][ni] = __builtin_amdgcn_mfma_f32_16x16x32_bf16(
              aF[mi], bF[ni], acc[mi][ni], 0, 0, 0);
    }
    __syncthreads();
  }
#pragma unroll
  for (int ni = 0; ni < 4; ++ni) {
    const int col = n0 + wn + ni * 16 + l16;
    const float bb = bias[col];
    const int hh = col >> 7, dd = col & 127;
#pragma unroll
    for (int mi = 0; mi < 2; ++mi) {
      const int rowb = m0 + wm + mi * 16 + kl * 4;
#pragma unroll
      for (int r = 0; r < 4; ++r) {
        const int row = rowb + r;
        if (row >= SEQ) continue;
        const unsigned short val = f2b(acc[mi][ni][r] + bb);
        if (which == 0) {
          Qb[((size_t)hh * SEQ + row) * HD + dd] = val;
        } else if (which == 1) {
          Kb[(size_t)(NCACHE + row) * MDIM + col] = val;
        } else {
          const int g = NCACHE + row;
          Vbt[(((size_t)(g >> 6) * NH + hh) * HD + dd) * 64 + (g & 63)] = val;
        }
      }
    }
  }
}

// ---------- Wo GEMM (r20, passing) ----------
__global__ __launch_bounds__(256) void gemm_o_k(
    const unsigned short* __restrict__ Ab, const unsigned short* __restrict__ Wt,
    const float* __restrict__ bias, float* __restrict__ outp) {
  __shared__ short As[64][72];
  __shared__ short Bs[128][72];
  const int tid = threadIdx.x;
  const int l = tid & 63, wv = tid >> 6;
  const int l16 = l & 15, kl = l >> 4;
  const int m0 = blockIdx.y * 64, n0 = blockIdx.x * 128;
  const int wm = (wv >> 1) * 32, wn = (wv & 1) * 64;
  f32x4 acc[2][4] = {};
  for (int k0 = 0; k0 < MDIM; k0 += 64) {
    {
      int m = tid >> 2, kq = tid & 3;
      int row = m0 + m, k = k0 + kq * 16;
      uint4 v0 = make_uint4(0, 0, 0, 0), v1 = make_uint4(0, 0, 0, 0);
      if (row < SEQ) {
        const unsigned short* p = Ab + ((size_t)(k >> 7) * SEQ + row) * HD + (k & 127);
        v0 = *(const uint4*)p;
        v1 = *(const uint4*)(p + 8);
      }
      *(uint4*)&As[m][kq * 16] = v0;
      *(uint4*)&As[m][kq * 16 + 8] = v1;
    }
    {
      int n = tid >> 1, kq = tid & 1;
      const unsigned short* p = Wt + (size_t)(n0 + n) * MDIM + k0 + kq * 32;
      uint4 v0 = *(const uint4*)p, v1 = *(const uint4*)(p + 8);
      uint4 v2 = *(const uint4*)(p + 16), v3 = *(const uint4*)(p + 24);
      *(uint4*)&Bs[n][kq * 32] = v0;
      *(uint4*)&Bs[n][kq * 32 + 8] = v1;
      *(uint4*)&Bs[n][kq * 32 + 16] = v2;
      *(uint4*)&Bs[n][kq * 32 + 24] = v3;
    }
    __syncthreads();
#pragma unroll
    for (int kk = 0; kk < 2; ++kk) {
      bf16x8 aF[2], bF[4];
#pragma unroll
      for (int mi = 0; mi < 2; ++mi)
        aF[mi] = *(const bf16x8*)&As[wm + mi * 16 + l16][kk * 32 + kl * 8];
#pragma unroll
      for (int ni = 0; ni < 4; ++ni)
        bF[ni] = *(const bf16x8*)&Bs[wn + ni * 16 + l16][kk * 32 + kl * 8];
#pragma unroll
      for (int mi = 0; mi < 2; ++mi)
#pragma unroll
        for (int ni = 0; ni < 4; ++ni)
          acc[mi][ni] = __builtin_amdgcn_mfma_f32_16x16x32_bf16(
              aF[mi], bF[ni], acc[mi][ni], 0, 0, 0);
    }
    __syncthreads();
  }
#pragma unroll
  for (int ni = 0; ni < 4; ++ni) {
    const int col = n0 + wn + ni * 16 + l16;
    const float bb = bias[col];
#pragma unroll
    for (int mi = 0; mi < 2; ++mi) {
      const int rowb = m0 + wm + mi * 16 + kl * 4;
#pragma unroll
      for (int r = 0; r < 4; ++r) {
        const int row = rowb + r;
        if (row >= SEQ) continue;
        outp[(size_t)row * MDIM + col] = acc[mi][ni][r] + bb;
      }
    }
  }
}

// ---------- RMSNorm + RoPE (r22, passing) ----------
__global__ __launch_bounds__(256) void rmsrope_k(
    unsigned short* __restrict__ Qb, unsigned short* __restrict__ Kb,
    const float* __restrict__ gq, const float* __restrict__ gk,
    const float* __restrict__ fr) {
  const int s = blockIdx.x, which = blockIdx.y;
  const float* g = which ? gk : gq;
  __shared__ float cs[64], sn[64], red[4];
  const int t = threadIdx.x;
  if (t < 64) {
    float a = fr[s * 64 + t];
    cs[t] = cosf(a);
    sn[t] = sinf(a);
  }
  const int c0 = t * 8;
  const int hh = c0 >> 7, dd = c0 & 127, p0 = dd >> 1;
  unsigned short* ptr = which
      ? Kb + (size_t)(NCACHE + s) * MDIM + c0
      : Qb + ((size_t)hh * SEQ + s) * HD + dd;
  bf16x8 v = *(const bf16x8*)ptr;
  float y[8];
#pragma unroll
  for (int i = 0; i < 8; ++i) y[i] = b2f((unsigned short)v[i]);
  float ssq = 0.f;
#pragma unroll
  for (int i = 0; i < 8; ++i) ssq += y[i] * y[i];
#pragma unroll
  for (int off = 32; off; off >>= 1) ssq += __shfl_xor(ssq, off);
  if ((t & 63) == 0) red[t >> 6] = ssq;
  __syncthreads();
  const float var = (red[0] + red[1] + red[2] + red[3]) * (1.0f / MDIM);
  const float rs = rsqrtf(var + 1e-6f);
  bf16x8 ov;
#pragma unroll
  for (int i = 0; i < 4; ++i) {
    float e = b2f(f2b(y[2 * i] * rs)) * g[c0 + 2 * i];
    float o = b2f(f2b(y[2 * i + 1] * rs)) * g[c0 + 2 * i + 1];
    float C = cs[p0 + i], S = sn[p0 + i];
    ov[2 * i]     = (short)f2b(e * C - o * S);
    ov[2 * i + 1] = (short)f2b(e * S + o * C);
  }
  *(bf16x8*)ptr = ov;
}

// ---------- flash attention (r23-exact, best: ~247 us): 3 barriers, setprio,
//            defer-max THR=8, wave-private P slab ----------
__global__ __launch_bounds__(512) void attn_part8_k(
    const unsigned short* __restrict__ Qb, const unsigned short* __restrict__ Kb,
    const unsigned short* __restrict__ Vbt, unsigned short* __restrict__ Opart,
    float* __restrict__ ml, int chunk, int S) {
  __shared__ short UN[9216];        // Kl: UN[j*136+d]; Pl: UN[(w*16+r)*72+c] (aliased, wave-private slabs)
  __shared__ short Vt[128][72];
  const int b = blockIdx.x;
  const int xcd = b & 7;
  const int r_ = b >> 3;
  const int qt = r_ % NQT2;
  const int g = (r_ / NQT2) * 8 + xcd;
  const int h = g & (NH - 1);
  const int z = g >> 4;
  const int tid = threadIdx.x, wv = tid >> 6, l = tid & 63;
  const int l16 = l & 15, kl = l >> 4;
  const float SCALE = 0.08838834764831845f;

  const int c0 = z * chunk;
  const int cend = min(c0 + chunk, LTOT);

  int qrow = qt * 128 + wv * 16 + l16;
  if (qrow > SEQ - 1) qrow = SEQ - 1;
  bf16x8 qf[4];
#pragma unroll
  for (int kk = 0; kk < 4; ++kk)
    qf[kk] = *(const bf16x8*)(Qb + ((size_t)h * SEQ + qrow) * HD + kk * 32 + kl * 8);

  f32x4 oacc[8] = {};
  float mrow[4] = {-1e30f, -1e30f, -1e30f, -1e30f};
  float lrow[4] = {0.f, 0.f, 0.f, 0.f};

  const int j0 = tid & 63, dq0 = tid >> 6, dq1 = (tid + 512) >> 6;
  const int dV0 = tid >> 3, dV1 = (tid + 512) >> 3, jo = tid & 7;
  const int hofs = h * HD;

  for (int kv0 = c0; kv0 < cend; kv0 += 64) {
    {
      const size_t krow = (size_t)(kv0 + j0) * MDIM + hofs;
      uint4 k0v = *(const uint4*)(Kb + krow + dq0 * 8);
      uint4 k1v = *(const uint4*)(Kb + krow + dq1 * 8);
      const size_t vbase = (((size_t)(kv0 >> 6) * NH + h) * HD) * 64;
      uint4 v0v = *(const uint4*)(Vbt + vbase + (size_t)dV0 * 64 + jo * 8);
      uint4 v1v = *(const uint4*)(Vbt + vbase + (size_t)dV1 * 64 + jo * 8);
      *(uint4*)&UN[j0 * 136 + dq0 * 8] = k0v;
      *(uint4*)&UN[j0 * 136 + dq1 * 8] = k1v;
      *(uint4*)&Vt[dV0][jo * 8] = v0v;
      *(uint4*)&Vt[dV1][jo * 8] = v1v;
    }
    __syncthreads();                                   // bar1: K/V staged

    f32x4 sa[4] = {};
    __builtin_amdgcn_s_setprio(1);
#pragma unroll
    for (int ni = 0; ni < 4; ++ni)
#pragma unroll
      for (int kk = 0; kk < 4; ++kk) {
        bf16x8 bK = *(const bf16x8*)&UN[(ni * 16 + l16) * 136 + kk * 32 + kl * 8];
        sa[ni] = __builtin_amdgcn_mfma_f32_16x16x32_bf16(qf[kk], bK, sa[ni], 0, 0, 0);
      }
    __builtin_amdgcn_s_setprio(0);
    __syncthreads();                                   // bar2: QK reads done (P aliases Kl)

    float sv[4][4];
    float pm[4] = {-1e30f, -1e30f, -1e30f, -1e30f};
#pragma unroll
    for (int ni = 0; ni < 4; ++ni) {
      int jg = kv0 + ni * 16 + l16;
      bool valid = jg < LTOT;
#pragma unroll
      for (int r = 0; r < 4; ++r) {
        float xs = valid ? sa[ni][r] * SCALE : -1e30f;
        sv[ni][r] = xs;
        pm[r] = fmaxf(pm[r], xs);
      }
    }
#pragma unroll
    for (int off = 1; off < 16; off <<= 1)
#pragma unroll
      for (int r = 0; r < 4; ++r) pm[r] = fmaxf(pm[r], __shfl_xor(pm[r], off));

    // T13 defer-max: only rescale when some row max grew by > 8
    bool grow = (pm[0] > mrow[0] + 8.f) || (pm[1] > mrow[1] + 8.f) ||
                (pm[2] > mrow[2] + 8.f) || (pm[3] > mrow[3] + 8.f);
    if (__any(grow)) {
#pragma unroll
      for (int r = 0; r < 4; ++r) {
        float mn = fmaxf(mrow[r], pm[r]);
        float sc = __expf(mrow[r] - mn);
        mrow[r] = mn;
        lrow[r] *= sc;
#pragma unroll
        for (int di = 0; di < 8; ++di) oacc[di][r] *= sc;
      }
    }

    float ps[4] = {0.f, 0.f, 0.f, 0.f};
#pragma unroll
    for (int ni = 0; ni < 4; ++ni)
#pragma unroll
      for (int r = 0; r < 4; ++r) {
        float p = __expf(sv[ni][r] - mrow[r]);   // bounded by e^8
        sv[ni][r] = p;
        ps[r] += p;
      }
#pragma unroll
    for (int off = 1; off < 16; off <<= 1)
#pragma unroll
      for (int r = 0; r < 4; ++r) ps[r] += __shfl_xor(ps[r], off);
#pragma unroll
    for (int r = 0; r < 4; ++r) lrow[r] += ps[r];

    // P write into own wave slab (wave-private; same-wave read below, no barrier)
#pragma unroll
    for (int ni = 0; ni < 4; ++ni)
#pragma unroll
      for (int r = 0; r < 4; ++r)
        UN[(wv * 16 + kl * 4 + r) * 72 + ni * 16 + l16] = (short)f2b(sv[ni][r]);

    __builtin_amdgcn_s_setprio(1);
#pragma unroll
    for (int di = 0; di < 8; ++di)
#pragma unroll
      for (int k2 = 0; k2 < 2; ++k2) {
        bf16x8 aP = *(const bf16x8*)&UN[(wv * 16 + l16) * 72 + k2 * 32 + kl * 8];
        bf16x8 bV = *(const bf16x8*)&Vt[di * 16 + l16][k2 * 32 + kl * 8];
        oacc[di] = __builtin_amdgcn_mfma_f32_16x16x32_bf16(aP, bV, oacc[di], 0, 0, 0);
      }
    __builtin_amdgcn_s_setprio(0);
    __syncthreads();                                   // bar3: all reads done; UN/Vt free
  }

  const size_t pbase = (((size_t)z * NH + h) * NQT2 + qt);
  const int row = wv * 16 + kl * 4;
#pragma unroll
  for (int r = 0; r < 4; ++r) {
    unsigned short* Op = Opart + (pbase * 128 + row + r) * HD;
#pragma unroll
    for (int di = 0; di < 8; ++di) Op[di * 16 + l16] = f2b(oacc[di][r]);
    ml[(pbase * 2 + 0) * 128 + row + r] = mrow[r];
    ml[(pbase * 2 + 1) * 128 + row + r] = lrow[r];
  }
}

// ---------- merge bf16 partials -> bf16 O in Qb (r21, passing) ----------
__global__ __launch_bounds__(512) void attn_merge3_k(
    const unsigned short* __restrict__ Opart, const float* __restrict__ ml,
    unsigned short* __restrict__ Qb, int S) {
  const int qt = blockIdx.x, h = blockIdx.y;
  const int t = threadIdx.x;
  const int row = t >> 2, d0 = (t & 3) * 32;
  const int q = qt * 128 + row;

  float M = -1e30f;
  for (int s = 0; s < S; ++s) {
    const size_t pbase = (((size_t)s * NH + h) * NQT2 + qt);
    M = fmaxf(M, ml[(pbase * 2 + 0) * 128 + row]);
  }
  float L = 0.f;
  float o[32];
#pragma unroll
  for (int i = 0; i < 32; ++i) o[i] = 0.f;
  for (int s = 0; s < S; ++s) {
    const size_t pbase = (((size_t)s * NH + h) * NQT2 + qt);
    const float ms = ml[(pbase * 2 + 0) * 128 + row];
    const float ls = ml[(pbase * 2 + 1) * 128 + row];
    const float w = __expf(ms - M);
    L += w * ls;
    const unsigned short* Op = Opart + (pbase * 128 + row) * HD + d0;
#pragma unroll
    for (int c = 0; c < 4; ++c) {
      bf16x8 v = *(const bf16x8*)(Op + c * 8);
#pragma unroll
      for (int i = 0; i < 8; ++i) o[c * 8 + i] += w * b2f((unsigned short)v[i]);
    }
  }
  if (q < SEQ) {
    const float inv = 1.f / L;
    unsigned short* op = Qb + ((size_t)h * SEQ + q) * HD + d0;
#pragma unroll
    for (int i = 0; i < 32; ++i) op[i] = f2b(o[i] * inv);
  }
}

extern "C" void kernel_launch(void* const* d_in, const int* in_sizes, int n_in,
                              void* d_out, int out_size, void* d_ws, size_t ws_size,
                              hipStream_t stream) {
  const float* x  = (const float*)d_in[0];
  const float* fr = (const float*)d_in[2];
  const float* Kc = (const float*)d_in[3];
  const float* Vc = (const float*)d_in[4];
  const float* Wq = (const float*)d_in[5];
  const float* bq = (const float*)d_in[6];
  const float* Wk = (const float*)d_in[7];
  const float* bk = (const float*)d_in[8];
  const float* Wv = (const float*)d_in[9];
  const float* bv = (const float*)d_in[10];
  const float* Wo = (const float*)d_in[11];
  const float* bo = (const float*)d_in[12];
  const float* gq = (const float*)d_in[13];
  const float* gk = (const float*)d_in[14];

  unsigned short* xb  = (unsigned short*)d_ws;
  unsigned short* Wto = xb + (size_t)SEQ * MDIM;
  unsigned short* Qb  = Wto + (size_t)MDIM * MDIM;
  unsigned short* Kb  = Qb + (size_t)NH * SEQ * HD;
  unsigned short* Vbt = Kb + (size_t)KROWS * MDIM;
  unsigned short* Wtq = Vbt + (size_t)NTILE * NH * HD * 64;
  unsigned short* Wtk = Wtq + (size_t)MDIM * MDIM;
  unsigned short* Wtv = Wtk + (size_t)MDIM * MDIM;

  const int S = SPLITS;
  unsigned short* Opart = Wtq;   // aliases Wt zone (dead after gemm_qkv)
  float* ml = (float*)(Opart + (size_t)S * NH * NQT2 * 128 * HD);

  hipMemsetAsync(Vbt + (size_t)(NTILE - 1) * NH * HD * 64, 0,
                 (size_t)NH * HD * 64 * 2, stream);

  const int n8x = SEQ * MDIM / 8;
  const int n8k = NCACHE * MDIM / 8;
  convflat_k<<<dim3((n8x + n8k + 255) / 256), 256, 0, stream>>>(x, xb, n8x, Kc, Kb, n8k);
  convvt_k<<<dim3(NCACHE / 64, NH), 256, 0, stream>>>(Vc, Vbt);
  convt_k<<<dim3(32, 32, 4), 256, 0, stream>>>(Wq, Wk, Wv, Wo, Wtq, Wtk, Wtv, Wto);

  gemm_qkv_k<<<dim3(48, 17), 256, 0, stream>>>(xb, Wtq, Wtk, Wtv, bq, bk, bv, Qb, Kb, Vbt);
  rmsrope_k<<<dim3(SEQ, 2), 256, 0, stream>>>(Qb, Kb, gq, gk, fr);

  const int chunk = ((NTILE + S - 1) / S) * 64;    // 25 tiles
  attn_part8_k<<<dim3(NQT2 * NH * S), 512, 0, stream>>>(Qb, Kb, Vbt, Opart, ml, chunk, S);
  attn_merge3_k<<<dim3(NQT2, NH), 512, 0, stream>>>(Opart, ml, Qb, S);

  gemm_o_k<<<dim3(16, 17), 256, 0, stream>>>(Qb, Wto, bo, (float*)d_out);
}